// Round 17
// baseline (69.947 us; speedup 1.0000x reference)
//
#include <hip/hip_runtime.h>
#include <hip/hip_bf16.h>

#define BS 64
#define C 512
#define DIN 256
#define DOUT 256
#define H 4
#define HD 64

typedef __attribute__((ext_vector_type(8))) short short8;
typedef __attribute__((ext_vector_type(4))) short short4v;
typedef __attribute__((ext_vector_type(4))) float f32x4;

// native RNE f32->bf16
__device__ __forceinline__ short bfc(float f) {
    union { __hip_bfloat16 h; unsigned short s; } u;
    u.h = __float2bfloat16(f);
    return (short)u.s;
}

__device__ __forceinline__ float bf2f(short v) {
    union { unsigned u; float f; } x;
    x.u = ((unsigned)(unsigned short)v) << 16;
    return x.f;
}

__device__ __forceinline__ short8 pack8n(const float* p) {
    short8 r;
#pragma unroll
    for (int i = 0; i < 8; ++i) r[i] = bfc(p[i]);
    return r;
}

// K0: one-time W/W1 -> bf16 in MFMA-B-FRAGMENT order (dense 1KB B-loads in k1/k3)
__global__ __launch_bounds__(256) void k0_prep(
    const float* __restrict__ W, const float* __restrict__ W1,
    short* __restrict__ Wbf, short* __restrict__ W1bf)
{
    const int idx = blockIdx.x * 256 + threadIdx.x;   // short8 slot
    const int l = idx & 63;
    const int lr = l & 15;
    const int g = l >> 4;
    if (idx < 8192) {                                  // W: 128 units x 64 lanes
        const int unit = idx >> 6;
        const int head = unit >> 5;
        const int ct = (unit >> 3) & 3;
        const int ks = unit & 7;
        const float* p = W + (size_t)(head * 64 + ct * 16 + lr) * DIN + ks * 32 + g * 8;
        float t[8];
        *(float4*)(t)     = *(const float4*)(p);
        *(float4*)(t + 4) = *(const float4*)(p + 4);
        *(short8*)(Wbf + idx * 8) = pack8n(t);
    } else if (idx < 10240) {                          // W1: 32 units x 64 lanes
        const int j = idx - 8192;
        const int unit = j >> 6;
        const int ct = unit >> 3;
        const int ks = unit & 7;
        const float* p = W1 + (size_t)(ct * 16 + lr) * DOUT + ks * 32 + g * 8;
        float t[8];
        *(float4*)(t)     = *(const float4*)(p);
        *(float4*)(t + 4) = *(const float4*)(p + 4);
        *(short8*)(W1bf + j * 8) = pack8n(t);
    }
}

// K1: Wh = h @ W^T. h tile bf16/XOR-swizzled LDS; W fragments dense;
// whT in MFMA-B-fragment order; ei/ej *log2e.
__global__ __launch_bounds__(256) void k1_gemm(
    const float* __restrict__ hsrc, const short* __restrict__ Wbf,
    const float* __restrict__ avec,
    short* __restrict__ whT, float* __restrict__ ei, float* __restrict__ ej)
{
    __shared__ __align__(16) short hs[64 * 256];      // 32KB bf16
    const int tid = threadIdx.x;
    const int l = tid & 63;
    const int w = tid >> 6;
    const int lr = l & 15;
    const int g = l >> 4;
    const int kg = g * 8;
    const int mtile = blockIdx.x;                     // 512 blocks
    const int row0 = mtile * 64;
    const float L2E = 1.44269504088896f;

#pragma unroll
    for (int it = 0; it < 8; ++it) {
        const int idx = tid + it * 256;               // 2048 slots: 64 rows x 32 col-groups
        const int row = idx >> 5;
        const int colg = idx & 31;
        const float* p = hsrc + (size_t)(row0 + row) * DIN + colg * 8;
        float t[8];
        *(float4*)(t)     = *(const float4*)(p);
        *(float4*)(t + 4) = *(const float4*)(p + 4);
        const int off = (row * 512 + colg * 16) ^ ((row & 7) << 4);
        *(short8*)((char*)hs + off) = pack8n(t);
    }
    __syncthreads();

    const int head = w;
    f32x4 acc[4][4];
#pragma unroll
    for (int i = 0; i < 4; ++i)
#pragma unroll
        for (int j = 0; j < 4; ++j) acc[i][j] = f32x4{0.f, 0.f, 0.f, 0.f};

    const short* wfb = Wbf + (size_t)head * 4 * 8 * 512 + l * 8;
    for (int k0 = 0; k0 < DIN; k0 += 32) {
        const int ks = k0 >> 5;
        short8 af[4];
#pragma unroll
        for (int rt = 0; rt < 4; ++rt) {
            const int row = rt * 16 + lr;
            const int off = (row * 512 + (k0 + kg) * 2) ^ ((row & 7) << 4);
            af[rt] = *(const short8*)((const char*)hs + off);
        }
        short8 bfr[4];
#pragma unroll
        for (int ct = 0; ct < 4; ++ct)
            bfr[ct] = *(const short8*)(wfb + (ct * 8 + ks) * 512);
#pragma unroll
        for (int rt = 0; rt < 4; ++rt)
#pragma unroll
            for (int ct = 0; ct < 4; ++ct)
                acc[rt][ct] = __builtin_amdgcn_mfma_f32_16x16x32_bf16(
                    af[rt], bfr[ct], acc[rt][ct], 0, 0, 0);
    }

    float avi[4], avj[4];
#pragma unroll
    for (int ct = 0; ct < 4; ++ct) {
        avi[ct] = avec[head * 2 * HD + ct * 16 + lr];
        avj[ct] = avec[head * 2 * HD + HD + ct * 16 + lr];
    }

    const int jt = mtile & 7;
    const int bb = mtile >> 3;
    short* fragb = whT + (size_t)(bb * H + head) * (HD * C);

#pragma unroll
    for (int rt = 0; rt < 4; ++rt) {
        const int lane2 = lr + 16 * ((rt & 1) * 2 + (g >> 1));
        const int t0 = (g & 1) * 4;
        const int half = rt >> 1;
#pragma unroll
        for (int ct = 0; ct < 4; ++ct) {
            short4v sv;
#pragma unroll
            for (int reg = 0; reg < 4; ++reg) sv[reg] = bfc(acc[rt][ct][reg]);
            *(short4v*)(fragb + (jt * 4 + ct) * 1024 + half * 512 + lane2 * 8 + t0) = sv;
        }
#pragma unroll
        for (int reg = 0; reg < 4; ++reg) {
            const int j = row0 + rt * 16 + g * 4 + reg;
            const int b = j >> 9;
            const int c = j & 511;
            float pi = 0.f, pj = 0.f;
#pragma unroll
            for (int ct = 0; ct < 4; ++ct) {
                pi += acc[rt][ct][reg] * avi[ct];
                pj += acc[rt][ct][reg] * avj[ct];
            }
#pragma unroll
            for (int off = 1; off < 16; off <<= 1) {
                pi += __shfl_xor(pi, off);
                pj += __shfl_xor(pj, off);
            }
            if (lr == 0) {
                ei[(b * H + head) * C + c] = pi * L2E;
                ej[(b * H + head) * C + c] = pj * L2E;
            }
        }
    }
}

// K2: per (b, 16-row i-tile); wave = head; grid 2048, bijective XCD swizzle.
// A_fc bf16 padded LDS; ej f32 LDS; RTZ P-pack with self-consistent lsum;
// raw v_exp_f32; V via walking pointer. jt-loop unrolled x2 so the scheduler
// overlaps the next iteration's V loads with this iteration's exp/pack chain.
__global__ __launch_bounds__(256) void k2_attn(
    const float* __restrict__ Afc, const short* __restrict__ whT,
    const float* __restrict__ ei, const float* __restrict__ ej,
    short* __restrict__ hpb)
{
    __shared__ __align__(16) short alds[16 * 520];    // 16,640 B
    __shared__ __align__(16) float elds[4 * 512];     //  8,192 B
    const int tid = threadIdx.x;
    const int l = tid & 63;
    const int hh = tid >> 6;
    const int swz = (blockIdx.x & 7) * 256 + (blockIdx.x >> 3);  // bijective, 2048%8==0
    const int b = swz >> 5;
    const int i0 = (swz & 31) * 16;
    const int lr = l & 15;
    const int kg = (l >> 4) * 8;

    {
        const float* asrc = Afc + ((size_t)b * C + i0) * C;
#pragma unroll
        for (int k = 0; k < 4; ++k) {
            const int idx = tid + k * 256;            // 1024 short8 groups: 16 rows x 64
            const int row = idx >> 6;
            const int colg = idx & 63;
            const float* p = asrc + row * 512 + colg * 8;
            float t[8];
            *(float4*)(t)     = *(const float4*)(p);
            *(float4*)(t + 4) = *(const float4*)(p + 4);
            *(short8*)(alds + row * 520 + colg * 8) = pack8n(t);
        }
        const float* ejsrc = ej + (size_t)b * H * C;
#pragma unroll
        for (int k = 0; k < 2; ++k) {
            const int idx = tid + k * 256;            // 512 float4 slots
            *(float4*)(elds + idx * 4) = *(const float4*)(ejsrc + idx * 4);
        }
    }
    __syncthreads();

    f32x4 O[4];
#pragma unroll
    for (int dt = 0; dt < 4; ++dt) O[dt] = f32x4{0.f, 0.f, 0.f, 0.f};
    float ls0 = 0.f, ls1 = 0.f, ls2 = 0.f, ls3 = 0.f;

    const float eiv = ei[(b * H + hh) * C + i0 + lr];    // already * log2(e)
    const short* vpw = whT + (size_t)(b * H + hh) * (HD * C) + l * 8;  // walking
    const short* arowp = alds + lr * 520;
    const float* ejl = elds + hh * 512;                  // already * log2(e)

#pragma unroll 2
    for (int jt = 0; jt < 8; ++jt) {
        const int j0 = jt * 64;

        short8 vf[4][2];
#pragma unroll
        for (int dt = 0; dt < 4; ++dt) {
            vf[dt][0] = *(const short8*)(vpw + jt * 4096 + dt * 1024);
            vf[dt][1] = *(const short8*)(vpw + jt * 4096 + dt * 1024 + 512);
        }

        float ejv[16];
        *(float4*)(ejv)      = *(const float4*)(ejl + j0 + kg);
        *(float4*)(ejv + 4)  = *(const float4*)(ejl + j0 + kg + 4);
        *(float4*)(ejv + 8)  = *(const float4*)(ejl + j0 + 32 + kg);
        *(float4*)(ejv + 12) = *(const float4*)(ejl + j0 + 32 + kg + 4);

        union { short8 s; unsigned u[4]; } a0, a1;
        a0.s = *(const short8*)(arowp + j0 + kg);
        a1.s = *(const short8*)(arowp + j0 + 32 + kg);
        float av[16];
#pragma unroll
        for (int i = 0; i < 4; ++i) {
            union { unsigned u; float f; } lo, hi;
            lo.u = a0.u[i] << 16;
            hi.u = a0.u[i] & 0xffff0000u;
            av[2 * i]     = lo.f;
            av[2 * i + 1] = hi.f;
            lo.u = a1.u[i] << 16;
            hi.u = a1.u[i] & 0xffff0000u;
            av[8 + 2 * i]     = lo.f;
            av[8 + 2 * i + 1] = hi.f;
        }

#pragma unroll
        for (int t = 0; t < 16; ++t) {
            const float z = eiv + ejv[t];
            const float zl = fmaxf(z, 0.2f * z);
            av[t] = __builtin_amdgcn_exp2f(zl * av[t]);
        }

        union { short8 s; unsigned u[4]; } P0, P1;
#pragma unroll
        for (int i = 0; i < 4; ++i) {
            const unsigned b0 = __float_as_uint(av[2 * i])     & 0xffff0000u;
            const unsigned b1 = __float_as_uint(av[2 * i + 1]) & 0xffff0000u;
            ls0 += __uint_as_float(b0);
            ls1 += __uint_as_float(b1);
            P0.u[i] = (b0 >> 16) | b1;
            const unsigned c0 = __float_as_uint(av[8 + 2 * i])     & 0xffff0000u;
            const unsigned c1 = __float_as_uint(av[8 + 2 * i + 1]) & 0xffff0000u;
            ls2 += __uint_as_float(c0);
            ls3 += __uint_as_float(c1);
            P1.u[i] = (c0 >> 16) | c1;
        }

#pragma unroll
        for (int dt = 0; dt < 4; ++dt) {
            O[dt] = __builtin_amdgcn_mfma_f32_16x16x32_bf16(P0.s, vf[dt][0], O[dt], 0, 0, 0);
            O[dt] = __builtin_amdgcn_mfma_f32_16x16x32_bf16(P1.s, vf[dt][1], O[dt], 0, 0, 0);
        }
    }

    float lsum = (ls0 + ls1) + (ls2 + ls3);
    lsum += __shfl_xor(lsum, 16);
    lsum += __shfl_xor(lsum, 32);
    const float inv = 1.0f / lsum;
    float fr[4];
#pragma unroll
    for (int reg = 0; reg < 4; ++reg)
        fr[reg] = __shfl(inv, (l >> 4) * 4 + reg);
#pragma unroll
    for (int dt = 0; dt < 4; ++dt)
#pragma unroll
        for (int reg = 0; reg < 4; ++reg) {
            const int c = i0 + (l >> 4) * 4 + reg;
            hpb[((size_t)b * C + c) * DOUT + hh * HD + dt * 16 + lr] =
                bfc(O[dt][reg] * fr[reg]);
        }
}

// K3: s = tanh(hp @ W1^T + b1) @ W2^T + b2. hp (bf16) staged XOR-swizzled LDS;
// W1 fragments dense (fragment-ordered W1bf).
__global__ __launch_bounds__(256) void k3_gate(
    const short* __restrict__ hpb, const short* __restrict__ W1bf,
    const float* __restrict__ b1, const float* __restrict__ W2,
    const float* __restrict__ b2, float* __restrict__ sgate)
{
    __shared__ __align__(16) short hs[64 * 256];      // 32KB
    const int t = threadIdx.x;
    const int l = t & 63;
    const int w = t >> 6;
    const int b = blockIdx.x >> 3;
    const int c0 = (blockIdx.x & 7) * 64;
    const int lr = l & 15;
    const int kg = (l >> 4) * 8;

    {
        const short* src = hpb + ((size_t)b * C + c0) * DOUT;
#pragma unroll
        for (int it = 0; it < 8; ++it) {
            const int idx = t + it * 256;             // 2048 slots: 64 rows x 32 groups
            const int row = idx >> 5;
            const int colg = idx & 31;
            const int off = (row * 512 + colg * 16) ^ ((row & 7) << 4);
            *(short8*)((char*)hs + off) = *(const short8*)(src + row * 256 + colg * 8);
        }
    }
    __syncthreads();

    f32x4 acc[4];
#pragma unroll
    for (int ct = 0; ct < 4; ++ct) acc[ct] = f32x4{0.f, 0.f, 0.f, 0.f};

    const int myrow = w * 16 + lr;
    const short* w1b = W1bf + l * 8;
    for (int k0 = 0; k0 < DOUT; k0 += 32) {
        const int ks = k0 >> 5;
        const int off = (myrow * 512 + (k0 + kg) * 2) ^ ((myrow & 7) << 4);
        const short8 af = *(const short8*)((const char*)hs + off);
#pragma unroll
        for (int ct = 0; ct < 4; ++ct) {
            const short8 bfr = *(const short8*)(w1b + (ct * 8 + ks) * 512);
            acc[ct] = __builtin_amdgcn_mfma_f32_16x16x32_bf16(af, bfr, acc[ct], 0, 0, 0);
        }
    }

    float b1v[4], w2v[4];
#pragma unroll
    for (int ct = 0; ct < 4; ++ct) {
        b1v[ct] = b1[ct * 16 + lr];
        w2v[ct] = W2[ct * 16 + lr];
    }
    const float b2v = b2[0];
#pragma unroll
    for (int reg = 0; reg < 4; ++reg) {
        float val = 0.f;
#pragma unroll
        for (int ct = 0; ct < 4; ++ct)
            val += tanhf(acc[ct][reg] + b1v[ct]) * w2v[ct];
#pragma unroll
        for (int off = 1; off < 16; off <<= 1) val += __shfl_xor(val, off);
        if (lr == 0)
            sgate[b * C + c0 + w * 16 + (l >> 4) * 4 + reg] = val + b2v;
    }
}

// K4a: per (b, 64-channel chunk): redundant softmax over sgate + weighted
// partial sum of bf16 hp rows (coalesced). 512 blocks.
__global__ __launch_bounds__(256) void k4a_partial(
    const short* __restrict__ hpb, const float* __restrict__ sgate,
    float* __restrict__ partial)
{
    __shared__ float red[16];
    __shared__ float wlds[64];
    const int t = threadIdx.x;
    const int b = blockIdx.x >> 3;
    const int c0 = (blockIdx.x & 7) * 64;
    const int l = t & 63, w = t >> 6;
    const float L2E = 1.44269504088896f;

    const float s0 = sgate[b * C + t], s1 = sgate[b * C + 256 + t];
    float mx = fmaxf(s0, s1);
#pragma unroll
    for (int off = 1; off < 64; off <<= 1) mx = fmaxf(mx, __shfl_xor(mx, off));
    if (l == 0) red[w] = mx;
    __syncthreads();
    mx = fmaxf(fmaxf(red[0], red[1]), fmaxf(red[2], red[3]));
    float sum = __builtin_amdgcn_exp2f((s0 - mx) * L2E) + __builtin_amdgcn_exp2f((s1 - mx) * L2E);
#pragma unroll
    for (int off = 1; off < 64; off <<= 1) sum += __shfl_xor(sum, off);
    if (l == 0) red[8 + w] = sum;
    __syncthreads();
    sum = red[8] + red[9] + red[10] + red[11];
    const float inv = 1.f / sum;
    if (t < 64)
        wlds[t] = __builtin_amdgcn_exp2f((sgate[b * C + c0 + t] - mx) * L2E) * inv;
    __syncthreads();

    float acc = 0.f;
    const short* base = hpb + ((size_t)b * C + c0) * DOUT + t;
#pragma unroll 4
    for (int c = 0; c < 64; ++c) acc += wlds[c] * bf2f(base[(size_t)c * DOUT]);
    partial[(size_t)blockIdx.x * DOUT + t] = acc;
}

// K4b: reduce the 8 chunk-partials per batch -> f32 out
__global__ __launch_bounds__(256) void k4b_reduce(
    const float* __restrict__ partial, float* __restrict__ out)
{
    const int t = threadIdx.x;
    const int b = blockIdx.x;
    float s = 0.f;
#pragma unroll
    for (int k = 0; k < 8; ++k)
        s += partial[(size_t)(b * 8 + k) * DOUT + t];
    out[b * DOUT + t] = s;
}

extern "C" void kernel_launch(void* const* d_in, const int* in_sizes, int n_in,
                              void* d_out, int out_size, void* d_ws, size_t ws_size,
                              hipStream_t stream) {
    const float* hsrc = (const float*)d_in[0];
    const float* Afc  = (const float*)d_in[1];
    const float* W    = (const float*)d_in[2];
    const float* avec = (const float*)d_in[3];
    const float* W1   = (const float*)d_in[4];
    const float* b1   = (const float*)d_in[5];
    const float* W2   = (const float*)d_in[6];
    const float* b2   = (const float*)d_in[7];

    char* ws = (char*)d_ws;
    short* whT   = (short*)(ws);                 // 16,777,216 B (fragment order)
    float* ei    = (float*)(ws + 16777216);      //    524,288 B
    float* ej    = (float*)(ws + 17301504);      //    524,288 B
    short* hpb   = (short*)(ws + 17825792);      // 16,777,216 B (bf16)
    float* sg    = (float*)(ws + 34603008);      //    131,072 B
    float* parts = (float*)(ws + 34734080);      //    524,288 B
    short* Wbf   = (short*)(ws + 35258368);      //    131,072 B (fragment order)
    short* W1bf  = (short*)(ws + 35389440);      //     32,768 B (fragment order)

    hipLaunchKernelGGL(k0_prep, dim3(40), dim3(256), 0, stream, W, W1, Wbf, W1bf);
    hipLaunchKernelGGL(k1_gemm, dim3(512), dim3(256), 0, stream, hsrc, Wbf, avec, whT, ei, ej);
    hipLaunchKernelGGL(k2_attn, dim3(2048), dim3(256), 0, stream, Afc, whT, ei, ej, hpb);
    hipLaunchKernelGGL(k3_gate, dim3(512), dim3(256), 0, stream, hpb, W1bf, b1, W2, b2, sg);
    hipLaunchKernelGGL(k4a_partial, dim3(512), dim3(256), 0, stream, hpb, sg, parts);
    hipLaunchKernelGGL(k4b_reduce, dim3(64), dim3(256), 0, stream, parts, (float*)d_out);
}

// Round 18
// 67.147 us; speedup vs baseline: 1.0417x; 1.0417x over previous
//
#include <hip/hip_runtime.h>
#include <hip/hip_bf16.h>

#define BS 64
#define C 512
#define DIN 256
#define DOUT 256
#define H 4
#define HD 64

typedef __attribute__((ext_vector_type(8))) short short8;
typedef __attribute__((ext_vector_type(4))) short short4v;
typedef __attribute__((ext_vector_type(4))) float f32x4;

// native RNE f32->bf16
__device__ __forceinline__ short bfc(float f) {
    union { __hip_bfloat16 h; unsigned short s; } u;
    u.h = __float2bfloat16(f);
    return (short)u.s;
}

__device__ __forceinline__ float bf2f(short v) {
    union { unsigned u; float f; } x;
    x.u = ((unsigned)(unsigned short)v) << 16;
    return x.f;
}

__device__ __forceinline__ short8 pack8n(const float* p) {
    short8 r;
#pragma unroll
    for (int i = 0; i < 8; ++i) r[i] = bfc(p[i]);
    return r;
}

// K0: one-time W/W1 -> bf16 in MFMA-B-FRAGMENT order (dense 1KB B-loads)
__global__ __launch_bounds__(256) void k0_prep(
    const float* __restrict__ W, const float* __restrict__ W1,
    short* __restrict__ Wbf, short* __restrict__ W1bf)
{
    const int idx = blockIdx.x * 256 + threadIdx.x;   // short8 slot
    const int l = idx & 63;
    const int lr = l & 15;
    const int g = l >> 4;
    if (idx < 8192) {                                  // W: 128 units x 64 lanes
        const int unit = idx >> 6;
        const int head = unit >> 5;
        const int ct = (unit >> 3) & 3;
        const int ks = unit & 7;
        const float* p = W + (size_t)(head * 64 + ct * 16 + lr) * DIN + ks * 32 + g * 8;
        float t[8];
        *(float4*)(t)     = *(const float4*)(p);
        *(float4*)(t + 4) = *(const float4*)(p + 4);
        *(short8*)(Wbf + idx * 8) = pack8n(t);
    } else if (idx < 10240) {                          // W1: 32 units x 64 lanes
        const int j = idx - 8192;
        const int unit = j >> 6;
        const int ct = unit >> 3;
        const int ks = unit & 7;
        const float* p = W1 + (size_t)(ct * 16 + lr) * DOUT + ks * 32 + g * 8;
        float t[8];
        *(float4*)(t)     = *(const float4*)(p);
        *(float4*)(t + 4) = *(const float4*)(p + 4);
        *(short8*)(W1bf + j * 8) = pack8n(t);
    }
}

// K1: Wh = h @ W^T. h tile bf16/XOR-swizzled LDS; W fragments dense;
// whT in MFMA-B-fragment order; ei/ej *log2e.
__global__ __launch_bounds__(256) void k1_gemm(
    const float* __restrict__ hsrc, const short* __restrict__ Wbf,
    const float* __restrict__ avec,
    short* __restrict__ whT, float* __restrict__ ei, float* __restrict__ ej)
{
    __shared__ __align__(16) short hs[64 * 256];      // 32KB bf16
    const int tid = threadIdx.x;
    const int l = tid & 63;
    const int w = tid >> 6;
    const int lr = l & 15;
    const int g = l >> 4;
    const int kg = g * 8;
    const int mtile = blockIdx.x;                     // 512 blocks
    const int row0 = mtile * 64;
    const float L2E = 1.44269504088896f;

#pragma unroll
    for (int it = 0; it < 8; ++it) {
        const int idx = tid + it * 256;               // 2048 slots: 64 rows x 32 col-groups
        const int row = idx >> 5;
        const int colg = idx & 31;
        const float* p = hsrc + (size_t)(row0 + row) * DIN + colg * 8;
        float t[8];
        *(float4*)(t)     = *(const float4*)(p);
        *(float4*)(t + 4) = *(const float4*)(p + 4);
        const int off = (row * 512 + colg * 16) ^ ((row & 7) << 4);
        *(short8*)((char*)hs + off) = pack8n(t);
    }
    __syncthreads();

    const int head = w;
    f32x4 acc[4][4];
#pragma unroll
    for (int i = 0; i < 4; ++i)
#pragma unroll
        for (int j = 0; j < 4; ++j) acc[i][j] = f32x4{0.f, 0.f, 0.f, 0.f};

    const short* wfb = Wbf + (size_t)head * 4 * 8 * 512 + l * 8;
    for (int k0 = 0; k0 < DIN; k0 += 32) {
        const int ks = k0 >> 5;
        short8 af[4];
#pragma unroll
        for (int rt = 0; rt < 4; ++rt) {
            const int row = rt * 16 + lr;
            const int off = (row * 512 + (k0 + kg) * 2) ^ ((row & 7) << 4);
            af[rt] = *(const short8*)((const char*)hs + off);
        }
        short8 bfr[4];
#pragma unroll
        for (int ct = 0; ct < 4; ++ct)
            bfr[ct] = *(const short8*)(wfb + (ct * 8 + ks) * 512);
#pragma unroll
        for (int rt = 0; rt < 4; ++rt)
#pragma unroll
            for (int ct = 0; ct < 4; ++ct)
                acc[rt][ct] = __builtin_amdgcn_mfma_f32_16x16x32_bf16(
                    af[rt], bfr[ct], acc[rt][ct], 0, 0, 0);
    }

    float avi[4], avj[4];
#pragma unroll
    for (int ct = 0; ct < 4; ++ct) {
        avi[ct] = avec[head * 2 * HD + ct * 16 + lr];
        avj[ct] = avec[head * 2 * HD + HD + ct * 16 + lr];
    }

    const int jt = mtile & 7;
    const int bb = mtile >> 3;
    short* fragb = whT + (size_t)(bb * H + head) * (HD * C);

#pragma unroll
    for (int rt = 0; rt < 4; ++rt) {
        const int lane2 = lr + 16 * ((rt & 1) * 2 + (g >> 1));
        const int t0 = (g & 1) * 4;
        const int half = rt >> 1;
#pragma unroll
        for (int ct = 0; ct < 4; ++ct) {
            short4v sv;
#pragma unroll
            for (int reg = 0; reg < 4; ++reg) sv[reg] = bfc(acc[rt][ct][reg]);
            *(short4v*)(fragb + (jt * 4 + ct) * 1024 + half * 512 + lane2 * 8 + t0) = sv;
        }
#pragma unroll
        for (int reg = 0; reg < 4; ++reg) {
            const int j = row0 + rt * 16 + g * 4 + reg;
            const int b = j >> 9;
            const int c = j & 511;
            float pi = 0.f, pj = 0.f;
#pragma unroll
            for (int ct = 0; ct < 4; ++ct) {
                pi += acc[rt][ct][reg] * avi[ct];
                pj += acc[rt][ct][reg] * avj[ct];
            }
#pragma unroll
            for (int off = 1; off < 16; off <<= 1) {
                pi += __shfl_xor(pi, off);
                pj += __shfl_xor(pj, off);
            }
            if (lr == 0) {
                ei[(b * H + head) * C + c] = pi * L2E;
                ej[(b * H + head) * C + c] = pj * L2E;
            }
        }
    }
}

// K2: per (b, 16-row i-tile); wave = head; grid 2048, bijective XCD swizzle.
// R15 main loop (A bf16 padded LDS; ej f32 LDS; RTZ P-pack w/ self-consistent
// lsum; native exp2; walking V pointer). FUSED GATE EPILOGUE: the block's 16
// complete h' rows are stashed bf16 in LDS (reusing alds), each wave computes
// its 16-n slice of tanh(hp@W1^T+b1)@W2^T via 8 MFMAs -> sgate. Kills k3's
// 16.7MB hpb re-read + launch.
__global__ __launch_bounds__(256) void k2_attn(
    const float* __restrict__ Afc, const short* __restrict__ whT,
    const float* __restrict__ ei, const float* __restrict__ ej,
    const short* __restrict__ W1bf, const float* __restrict__ b1,
    const float* __restrict__ W2, const float* __restrict__ b2,
    short* __restrict__ hpb, float* __restrict__ sgate)
{
    __shared__ __align__(16) short alds[16 * 520];    // 16,640 B (reused as gate tile)
    __shared__ __align__(16) float elds[4 * 512];     //  8,192 B
    __shared__ float ps[4][16];
    const int tid = threadIdx.x;
    const int l = tid & 63;
    const int hh = tid >> 6;
    const int swz = (blockIdx.x & 7) * 256 + (blockIdx.x >> 3);  // bijective, 2048%8==0
    const int b = swz >> 5;
    const int i0 = (swz & 31) * 16;
    const int lr = l & 15;
    const int kg = (l >> 4) * 8;

    {
        const float* asrc = Afc + ((size_t)b * C + i0) * C;
#pragma unroll
        for (int k = 0; k < 4; ++k) {
            const int idx = tid + k * 256;            // 1024 short8 groups: 16 rows x 64
            const int row = idx >> 6;
            const int colg = idx & 63;
            const float* p = asrc + row * 512 + colg * 8;
            float t[8];
            *(float4*)(t)     = *(const float4*)(p);
            *(float4*)(t + 4) = *(const float4*)(p + 4);
            *(short8*)(alds + row * 520 + colg * 8) = pack8n(t);
        }
        const float* ejsrc = ej + (size_t)b * H * C;
#pragma unroll
        for (int k = 0; k < 2; ++k) {
            const int idx = tid + k * 256;            // 512 float4 slots
            *(float4*)(elds + idx * 4) = *(const float4*)(ejsrc + idx * 4);
        }
    }
    __syncthreads();

    f32x4 O[4];
#pragma unroll
    for (int dt = 0; dt < 4; ++dt) O[dt] = f32x4{0.f, 0.f, 0.f, 0.f};
    float ls0 = 0.f, ls1 = 0.f, ls2 = 0.f, ls3 = 0.f;

    const float eiv = ei[(b * H + hh) * C + i0 + lr];    // already * log2(e)
    const short* vpw = whT + (size_t)(b * H + hh) * (HD * C) + l * 8;  // walking
    const short* arowp = alds + lr * 520;
    const float* ejl = elds + hh * 512;                  // already * log2(e)

    for (int jt = 0; jt < 8; ++jt) {
        const int j0 = jt * 64;

        short8 vf[4][2];
#pragma unroll
        for (int dt = 0; dt < 4; ++dt) {
            vf[dt][0] = *(const short8*)(vpw + dt * 1024);
            vf[dt][1] = *(const short8*)(vpw + dt * 1024 + 512);
        }

        float ejv[16];
        *(float4*)(ejv)      = *(const float4*)(ejl + j0 + kg);
        *(float4*)(ejv + 4)  = *(const float4*)(ejl + j0 + kg + 4);
        *(float4*)(ejv + 8)  = *(const float4*)(ejl + j0 + 32 + kg);
        *(float4*)(ejv + 12) = *(const float4*)(ejl + j0 + 32 + kg + 4);

        union { short8 s; unsigned u[4]; } a0, a1;
        a0.s = *(const short8*)(arowp + j0 + kg);
        a1.s = *(const short8*)(arowp + j0 + 32 + kg);
        float av[16];
#pragma unroll
        for (int i = 0; i < 4; ++i) {
            union { unsigned u; float f; } lo, hi;
            lo.u = a0.u[i] << 16;
            hi.u = a0.u[i] & 0xffff0000u;
            av[2 * i]     = lo.f;
            av[2 * i + 1] = hi.f;
            lo.u = a1.u[i] << 16;
            hi.u = a1.u[i] & 0xffff0000u;
            av[8 + 2 * i]     = lo.f;
            av[8 + 2 * i + 1] = hi.f;
        }

#pragma unroll
        for (int t = 0; t < 16; ++t) {
            const float z = eiv + ejv[t];
            const float zl = fmaxf(z, 0.2f * z);
            av[t] = __builtin_amdgcn_exp2f(zl * av[t]);
        }

        union { short8 s; unsigned u[4]; } P0, P1;
#pragma unroll
        for (int i = 0; i < 4; ++i) {
            const unsigned b0 = __float_as_uint(av[2 * i])     & 0xffff0000u;
            const unsigned b1 = __float_as_uint(av[2 * i + 1]) & 0xffff0000u;
            ls0 += __uint_as_float(b0);
            ls1 += __uint_as_float(b1);
            P0.u[i] = (b0 >> 16) | b1;
            const unsigned c0 = __float_as_uint(av[8 + 2 * i])     & 0xffff0000u;
            const unsigned c1 = __float_as_uint(av[8 + 2 * i + 1]) & 0xffff0000u;
            ls2 += __uint_as_float(c0);
            ls3 += __uint_as_float(c1);
            P1.u[i] = (c0 >> 16) | c1;
        }

#pragma unroll
        for (int dt = 0; dt < 4; ++dt) {
            O[dt] = __builtin_amdgcn_mfma_f32_16x16x32_bf16(P0.s, vf[dt][0], O[dt], 0, 0, 0);
            O[dt] = __builtin_amdgcn_mfma_f32_16x16x32_bf16(P1.s, vf[dt][1], O[dt], 0, 0, 0);
        }
        vpw += 4096;
    }

    float lsum = (ls0 + ls1) + (ls2 + ls3);
    lsum += __shfl_xor(lsum, 16);
    lsum += __shfl_xor(lsum, 32);
    const float inv = 1.0f / lsum;
    float fr[4];
#pragma unroll
    for (int reg = 0; reg < 4; ++reg)
        fr[reg] = __shfl(inv, (l >> 4) * 4 + reg);

    // ---- write hp (bf16) + stash gate tile in LDS (alds reused: gt[16][264]) ----
    __syncthreads();                                  // all alds/elds reads done
    short* gt = alds;
#pragma unroll
    for (int dt = 0; dt < 4; ++dt)
#pragma unroll
        for (int reg = 0; reg < 4; ++reg) {
            const int cl = (l >> 4) * 4 + reg;
            const short v = bfc(O[dt][reg] * fr[reg]);
            hpb[((size_t)b * C + i0 + cl) * DOUT + hh * HD + dt * 16 + lr] = v;
            gt[cl * 264 + hh * 64 + dt * 16 + lr] = v;
        }
    __syncthreads();

    // ---- fused gate: wave hh computes y[16c x 16n] (n = hh*16..) over k=256 ----
    f32x4 gacc = f32x4{0.f, 0.f, 0.f, 0.f};
    const short* w1b = W1bf + (hh * 8) * 512 + l * 8;
#pragma unroll
    for (int ks = 0; ks < 8; ++ks) {
        const short8 ga8 = *(const short8*)(gt + lr * 264 + ks * 32 + kg);
        const short8 gb8 = *(const short8*)(w1b + ks * 512);
        gacc = __builtin_amdgcn_mfma_f32_16x16x32_bf16(ga8, gb8, gacc, 0, 0, 0);
    }
    const float b1v = b1[hh * 16 + lr];
    const float w2v = W2[hh * 16 + lr];
#pragma unroll
    for (int reg = 0; reg < 4; ++reg) {
        float tv = tanhf(gacc[reg] + b1v) * w2v;      // lane: c=(l>>4)*4+reg, n=hh*16+lr
#pragma unroll
        for (int off = 1; off < 16; off <<= 1) tv += __shfl_xor(tv, off);
        if (lr == 0) ps[hh][(l >> 4) * 4 + reg] = tv;
    }
    __syncthreads();
    if (tid < 16)
        sgate[b * C + i0 + tid] = (ps[0][tid] + ps[1][tid]) + (ps[2][tid] + ps[3][tid]) + b2[0];
}

// K4a: per (b, 64-channel chunk): redundant softmax over sgate + weighted
// partial sum of bf16 hp rows (coalesced). 512 blocks.
__global__ __launch_bounds__(256) void k4a_partial(
    const short* __restrict__ hpb, const float* __restrict__ sgate,
    float* __restrict__ partial)
{
    __shared__ float red[16];
    __shared__ float wlds[64];
    const int t = threadIdx.x;
    const int b = blockIdx.x >> 3;
    const int c0 = (blockIdx.x & 7) * 64;
    const int l = t & 63, w = t >> 6;
    const float L2E = 1.44269504088896f;

    const float s0 = sgate[b * C + t], s1 = sgate[b * C + 256 + t];
    float mx = fmaxf(s0, s1);
#pragma unroll
    for (int off = 1; off < 64; off <<= 1) mx = fmaxf(mx, __shfl_xor(mx, off));
    if (l == 0) red[w] = mx;
    __syncthreads();
    mx = fmaxf(fmaxf(red[0], red[1]), fmaxf(red[2], red[3]));
    float sum = __builtin_amdgcn_exp2f((s0 - mx) * L2E) + __builtin_amdgcn_exp2f((s1 - mx) * L2E);
#pragma unroll
    for (int off = 1; off < 64; off <<= 1) sum += __shfl_xor(sum, off);
    if (l == 0) red[8 + w] = sum;
    __syncthreads();
    sum = red[8] + red[9] + red[10] + red[11];
    const float inv = 1.f / sum;
    if (t < 64)
        wlds[t] = __builtin_amdgcn_exp2f((sgate[b * C + c0 + t] - mx) * L2E) * inv;
    __syncthreads();

    float acc = 0.f;
    const short* base = hpb + ((size_t)b * C + c0) * DOUT + t;
#pragma unroll 4
    for (int c = 0; c < 64; ++c) acc += wlds[c] * bf2f(base[(size_t)c * DOUT]);
    partial[(size_t)blockIdx.x * DOUT + t] = acc;
}

// K4b: reduce the 8 chunk-partials per batch -> f32 out
__global__ __launch_bounds__(256) void k4b_reduce(
    const float* __restrict__ partial, float* __restrict__ out)
{
    const int t = threadIdx.x;
    const int b = blockIdx.x;
    float s = 0.f;
#pragma unroll
    for (int k = 0; k < 8; ++k)
        s += partial[(size_t)(b * 8 + k) * DOUT + t];
    out[b * DOUT + t] = s;
}

extern "C" void kernel_launch(void* const* d_in, const int* in_sizes, int n_in,
                              void* d_out, int out_size, void* d_ws, size_t ws_size,
                              hipStream_t stream) {
    const float* hsrc = (const float*)d_in[0];
    const float* Afc  = (const float*)d_in[1];
    const float* W    = (const float*)d_in[2];
    const float* avec = (const float*)d_in[3];
    const float* W1   = (const float*)d_in[4];
    const float* b1   = (const float*)d_in[5];
    const float* W2   = (const float*)d_in[6];
    const float* b2   = (const float*)d_in[7];

    char* ws = (char*)d_ws;
    short* whT   = (short*)(ws);                 // 16,777,216 B (fragment order)
    float* ei    = (float*)(ws + 16777216);      //    524,288 B
    float* ej    = (float*)(ws + 17301504);      //    524,288 B
    short* hpb   = (short*)(ws + 17825792);      // 16,777,216 B (bf16)
    float* sg    = (float*)(ws + 34603008);      //    131,072 B
    float* parts = (float*)(ws + 34734080);      //    524,288 B
    short* Wbf   = (short*)(ws + 35258368);      //    131,072 B (fragment order)
    short* W1bf  = (short*)(ws + 35389440);      //     32,768 B (fragment order)

    hipLaunchKernelGGL(k0_prep, dim3(40), dim3(256), 0, stream, W, W1, Wbf, W1bf);
    hipLaunchKernelGGL(k1_gemm, dim3(512), dim3(256), 0, stream, hsrc, Wbf, avec, whT, ei, ej);
    hipLaunchKernelGGL(k2_attn, dim3(2048), dim3(256), 0, stream,
                       Afc, whT, ei, ej, W1bf, b1, W2, b2, hpb, sg);
    hipLaunchKernelGGL(k4a_partial, dim3(512), dim3(256), 0, stream, hpb, sg, parts);
    hipLaunchKernelGGL(k4b_reduce, dim3(64), dim3(256), 0, stream, parts, (float*)d_out);
}